// Round 2
// baseline (546.417 us; speedup 1.0000x reference)
//
#include <hip/hip_runtime.h>
#include <hip/hip_bf16.h>

#define Bv 32
#define Nv 4096
#define Dv 64
#define Hv 64
#define Fv 128
#define Ev 65536
#define Sv 2
#define Ov 128
#define Mv 5

using short8  = __attribute__((ext_vector_type(8))) short;
using floatx4 = __attribute__((ext_vector_type(4))) float;

__device__ __forceinline__ float bflo(unsigned u){ unsigned v = u << 16; float f; __builtin_memcpy(&f, &v, 4); return f; }
__device__ __forceinline__ float bfhi(unsigned u){ unsigned v = u & 0xffff0000u; float f; __builtin_memcpy(&f, &v, 4); return f; }
__device__ __forceinline__ unsigned short f2bf(float f){
  unsigned x; __builtin_memcpy(&x, &f, 4);
  x += 0x7fffu + ((x >> 16) & 1u);           // RNE
  return (unsigned short)(x >> 16);
}
__device__ __forceinline__ unsigned bfpack(float a, float b){
  return (unsigned)f2bf(a) | ((unsigned)f2bf(b) << 16);
}

// ---------------- CSR build ----------------
__global__ void k_zero(int* __restrict__ p, int n){
  int i = blockIdx.x * 256 + threadIdx.x;
  if(i < n) p[i] = 0;
}

__global__ void k_hist(const int* __restrict__ rows, int* __restrict__ deg){
  int i = blockIdx.x * 256 + threadIdx.x;           // [0, S*E)
  int s = i >> 16;                                  // E = 65536
  int r = rows[i];
  atomicAdd(&deg[s * Nv + r], 1);
}

__global__ void k_scan(const int* __restrict__ deg, int* __restrict__ rowptr, int* __restrict__ cursor){
  __shared__ int part[256];
  __shared__ int sbase[256];
  int t = threadIdx.x;
  for(int s = 0; s < Sv; s++){
    int loc[16]; int sum = 0;
    #pragma unroll
    for(int i = 0; i < 16; i++){ loc[i] = deg[s * Nv + t * 16 + i]; sum += loc[i]; }
    part[t] = sum;
    __syncthreads();
    if(t == 0){ int run = 0; for(int i = 0; i < 256; i++){ int v = part[i]; sbase[i] = run; run += v; } }
    __syncthreads();
    int run = sbase[t];
    #pragma unroll
    for(int i = 0; i < 16; i++){
      int idx = t * 16 + i;
      rowptr[s * (Nv + 1) + idx] = run;
      cursor[s * Nv + idx] = run;
      run += loc[i];
    }
    if(t == 255) rowptr[s * (Nv + 1) + Nv] = run;
    __syncthreads();
  }
}

// pack (col:u16 low, bf16(val):u16 high) -> 4 B/edge
__global__ void k_scatter(const int* __restrict__ rows, const int* __restrict__ cols,
                          const float* __restrict__ vals, int* __restrict__ cursor,
                          unsigned* __restrict__ pk){
  int i = blockIdx.x * 256 + threadIdx.x;           // [0, S*E)
  int s = i >> 16;
  int r = rows[i];
  int p = atomicAdd(&cursor[s * Nv + r], 1);
  pk[(s << 16) + p] = (unsigned)cols[i] | ((unsigned)f2bf(vals[i]) << 16);
}

// ---------------- build X0 (bf16, layout [b][n][f]), XCD-affine: b-plane group = blockIdx&7
__global__ void k_buildx0(const float* __restrict__ inp, const float* __restrict__ st,
                          unsigned* __restrict__ X0u){
  const int tid = threadIdx.x;
  const int b  = (blockIdx.x & 7) * 4 + ((blockIdx.x >> 3) & 3);
  const int nc = blockIdx.x >> 5;                   // 0..1023
  const int n  = nc * 4 + (tid >> 6);
  const int f2 = tid & 63;
  float2 v;
  if(f2 < 32) v = *(const float2*)(inp + (size_t)b * Nv * Dv + (size_t)n * Dv + f2 * 2);
  else        v = *(const float2*)(st  + (size_t)b * Nv * Hv + (size_t)n * Hv + (f2 - 32) * 2);
  X0u[(size_t)(b * Nv + n) * 64 + f2] = bfpack(v.x, v.y);
}

// ---------------- weights: Wb[m][o][f] bf16 (transposed for gemm_bt) ----------------
__global__ void k_wb(const float* __restrict__ wg, unsigned short* __restrict__ Wb){
  int t = blockIdx.x * 256 + threadIdx.x;           // [0, M*O*F)
  if(t >= Mv * Ov * Fv) return;
  int f = t & (Fv - 1);
  int o = (t >> 7) & (Ov - 1);
  int m = t >> 14;
  Wb[t] = f2bf(wg[(f * Mv + m) * Ov + o]);
}

// ---------------- SpMM, one support per launch, XCD-affine ----------------
// b-plane group bg = blockIdx&7 (4 planes, 4 MiB src slice == one XCD L2).
// CSR/xprev loads and dst stores are non-temporal so the src slice stays resident.
__launch_bounds__(256)
__global__ void k_spmm2(const unsigned* __restrict__ src, unsigned* __restrict__ dst,
                        const unsigned* __restrict__ xprev,
                        const int* __restrict__ rowptr, const unsigned* __restrict__ pk){
  const int lane = threadIdx.x & 63;
  const int wv   = threadIdx.x >> 6;
  const int bg   = blockIdx.x & 7;
  const int rb   = blockIdx.x >> 3;                 // 0..1023
  const int r    = rb * 4 + wv;
  const int j0 = rowptr[r];
  const int j1 = rowptr[r + 1];
  const unsigned* __restrict__ sb0 = src + (size_t)(bg * 4 + 0) * (Nv * 64);
  const unsigned* __restrict__ sb1 = src + (size_t)(bg * 4 + 1) * (Nv * 64);
  const unsigned* __restrict__ sb2 = src + (size_t)(bg * 4 + 2) * (Nv * 64);
  const unsigned* __restrict__ sb3 = src + (size_t)(bg * 4 + 3) * (Nv * 64);

  float a00 = 0.f, a01 = 0.f, a10 = 0.f, a11 = 0.f;
  float a20 = 0.f, a21 = 0.f, a30 = 0.f, a31 = 0.f;
  for(int j = j0; j < j1; j++){
    const unsigned e = __builtin_nontemporal_load(pk + j);
    const int off = (int)(e & 0xffffu) * 64 + lane;
    const float v = bfhi(e);
    const unsigned x0 = sb0[off];
    const unsigned x1 = sb1[off];
    const unsigned x2 = sb2[off];
    const unsigned x3 = sb3[off];
    a00 += v * bflo(x0); a01 += v * bfhi(x0);
    a10 += v * bflo(x1); a11 += v * bfhi(x1);
    a20 += v * bflo(x2); a21 += v * bfhi(x2);
    a30 += v * bflo(x3); a31 += v * bfhi(x3);
  }
  const int roff = r * 64 + lane;
  if(xprev){
    const unsigned p0 = __builtin_nontemporal_load(xprev + (size_t)(bg * 4 + 0) * (Nv * 64) + roff);
    const unsigned p1 = __builtin_nontemporal_load(xprev + (size_t)(bg * 4 + 1) * (Nv * 64) + roff);
    const unsigned p2 = __builtin_nontemporal_load(xprev + (size_t)(bg * 4 + 2) * (Nv * 64) + roff);
    const unsigned p3 = __builtin_nontemporal_load(xprev + (size_t)(bg * 4 + 3) * (Nv * 64) + roff);
    a00 = 2.f * a00 - bflo(p0); a01 = 2.f * a01 - bfhi(p0);
    a10 = 2.f * a10 - bflo(p1); a11 = 2.f * a11 - bfhi(p1);
    a20 = 2.f * a20 - bflo(p2); a21 = 2.f * a21 - bfhi(p2);
    a30 = 2.f * a30 - bflo(p3); a31 = 2.f * a31 - bfhi(p3);
  }
  __builtin_nontemporal_store(bfpack(a00, a01), dst + (size_t)(bg * 4 + 0) * (Nv * 64) + roff);
  __builtin_nontemporal_store(bfpack(a10, a11), dst + (size_t)(bg * 4 + 1) * (Nv * 64) + roff);
  __builtin_nontemporal_store(bfpack(a20, a21), dst + (size_t)(bg * 4 + 2) * (Nv * 64) + roff);
  __builtin_nontemporal_store(bfpack(a30, a31), dst + (size_t)(bg * 4 + 3) * (Nv * 64) + roff);
}

// ---------------- GEMM: out[r][o] = sum_m A_m[r][:] . Wb[m][o][:] + bias[o] ----------------
__launch_bounds__(256)
__global__ void k_gemm(const unsigned short* __restrict__ X0,
                       const unsigned short* __restrict__ X1a,
                       const unsigned short* __restrict__ X2a,
                       const unsigned short* __restrict__ X1b,
                       const unsigned short* __restrict__ X2b,
                       const unsigned short* __restrict__ Wb,
                       const float* __restrict__ bias,
                       float* __restrict__ out){
  __shared__ unsigned short Asm[128 * 32];
  __shared__ unsigned short Bsm[128 * 32];
  const unsigned short* Am[5] = {X0, X1a, X2a, X1b, X2b};
  const int tid  = threadIdx.x;
  const int lane = tid & 63, wv = tid >> 6;
  const int wm = wv >> 1, wn = wv & 1;
  const int lrow = lane & 15, quad = lane >> 4;
  const size_t r0 = (size_t)blockIdx.x * 128;

  floatx4 acc[4][4] = {};

  #pragma unroll
  for(int m = 0; m < 5; m++){
    const unsigned short* Ab = Am[m] + r0 * Fv;
    const unsigned short* Bb = Wb + m * (Ov * Fv);
    #pragma unroll
    for(int kk = 0; kk < Fv; kk += 32){
      __syncthreads();
      #pragma unroll
      for(int p = 0; p < 2; p++){
        int idx = p * 256 + tid;
        int row = idx >> 2, seg = idx & 3;
        *(uint4*)(&Asm[row * 32 + seg * 8]) = *(const uint4*)(Ab + (size_t)row * Fv + kk + seg * 8);
        *(uint4*)(&Bsm[row * 32 + seg * 8]) = *(const uint4*)(Bb + row * Fv + kk + seg * 8);
      }
      __syncthreads();
      short8 af[4], bfr[4];
      #pragma unroll
      for(int t = 0; t < 4; t++){
        af[t]  = *(const short8*)(&Asm[(wm * 64 + t * 16 + lrow) * 32 + quad * 8]);
        bfr[t] = *(const short8*)(&Bsm[(wn * 64 + t * 16 + lrow) * 32 + quad * 8]);
      }
      #pragma unroll
      for(int ti = 0; ti < 4; ti++)
        #pragma unroll
        for(int tj = 0; tj < 4; tj++)
          acc[ti][tj] = __builtin_amdgcn_mfma_f32_16x16x32_bf16(af[ti], bfr[tj], acc[ti][tj], 0, 0, 0);
    }
  }

  #pragma unroll
  for(int ti = 0; ti < 4; ti++){
    #pragma unroll
    for(int tj = 0; tj < 4; tj++){
      const int col = wn * 64 + tj * 16 + lrow;
      const float bv = bias[col];
      const size_t rbase = r0 + wm * 64 + ti * 16 + quad * 4;
      #pragma unroll
      for(int t = 0; t < 4; t++){
        out[(rbase + t) * Ov + col] = acc[ti][tj][t] + bv;
      }
    }
  }
}

extern "C" void kernel_launch(void* const* d_in, const int* in_sizes, int n_in,
                              void* d_out, int out_size, void* d_ws, size_t ws_size,
                              hipStream_t stream) {
  (void)in_sizes; (void)n_in; (void)out_size; (void)ws_size;
  const float* inp  = (const float*)d_in[0];
  const float* st   = (const float*)d_in[1];
  const int*   rows = (const int*)d_in[2];
  const int*   cols = (const int*)d_in[3];
  const float* vals = (const float*)d_in[4];
  const float* wght = (const float*)d_in[5];
  const float* bias = (const float*)d_in[6];
  float* out = (float*)d_out;

  char* w = (char*)d_ws;
  const size_t SZX = (size_t)Bv * Nv * Fv * 2;      // 32 MiB per bf16 matrix
  unsigned short* X0  = (unsigned short*)(w);
  unsigned short* X1a = (unsigned short*)(w + SZX);
  unsigned short* X2a = (unsigned short*)(w + 2 * SZX);
  unsigned short* X1b = (unsigned short*)(w + 3 * SZX);
  unsigned short* X2b = (unsigned short*)(w + 4 * SZX);
  unsigned short* Wb  = (unsigned short*)(w + 5 * SZX);     // 160 KiB used, 256 KiB reserved
  char* p2 = w + 5 * SZX + 262144;
  int* deg    = (int*)p2;                       // [S*N]
  int* cursor = deg + Sv * Nv;                  // [S*N]
  int* rowptr = cursor + Sv * Nv;               // [S*(N+1)]
  unsigned* pk = (unsigned*)(rowptr + Sv * (Nv + 1) + 62);  // [S*E] packed col|bf16val

  k_zero<<<(Sv * Nv + 255) / 256, 256, 0, stream>>>(deg, Sv * Nv);
  k_hist<<<Sv * Ev / 256, 256, 0, stream>>>(rows, deg);
  k_scan<<<1, 256, 0, stream>>>(deg, rowptr, cursor);
  k_scatter<<<Sv * Ev / 256, 256, 0, stream>>>(rows, cols, vals, cursor, pk);
  k_buildx0<<<(Bv * Nv * 64) / 256, 256, 0, stream>>>(inp, st, (unsigned*)X0);
  k_wb<<<(Mv * Ov * Fv + 255) / 256, 256, 0, stream>>>(wght, Wb);

  // step 1: x1 = A_s x0   (one support per launch, XCD-affine)
  k_spmm2<<<8192, 256, 0, stream>>>((const unsigned*)X0, (unsigned*)X1a,
                                    (const unsigned*)nullptr, rowptr, pk);
  k_spmm2<<<8192, 256, 0, stream>>>((const unsigned*)X0, (unsigned*)X1b,
                                    (const unsigned*)nullptr, rowptr + (Nv + 1), pk + Ev);
  // step 2: x2 = 2 A_s x1 - x0
  k_spmm2<<<8192, 256, 0, stream>>>((const unsigned*)X1a, (unsigned*)X2a,
                                    (const unsigned*)X0, rowptr, pk);
  k_spmm2<<<8192, 256, 0, stream>>>((const unsigned*)X1b, (unsigned*)X2b,
                                    (const unsigned*)X0, rowptr + (Nv + 1), pk + Ev);

  k_gemm<<<(Bv * Nv) / 128, 256, 0, stream>>>(X0, X1a, X2a, X1b, X2b, Wb, bias, out);
}

// Round 4
// 338.958 us; speedup vs baseline: 1.6121x; 1.6121x over previous
//
#include <hip/hip_runtime.h>
#include <hip/hip_bf16.h>

#define Bv 32
#define Nv 4096
#define Dv 64
#define Hv 64
#define Fv 128
#define Ev 65536
#define Sv 2
#define Ov 128
#define Mv 5

typedef unsigned int uint;
using short8  = __attribute__((ext_vector_type(8))) short;
using floatx4 = __attribute__((ext_vector_type(4))) float;
using f32x2   = __attribute__((ext_vector_type(2))) float;
using uintx4  = __attribute__((ext_vector_type(4))) uint;

#define AS1 __attribute__((address_space(1)))
#define AS3 __attribute__((address_space(3)))

__device__ __forceinline__ float bflo(uint u){ uint v = u << 16; float f; __builtin_memcpy(&f, &v, 4); return f; }
__device__ __forceinline__ float bfhi(uint u){ uint v = u & 0xffff0000u; float f; __builtin_memcpy(&f, &v, 4); return f; }
__device__ __forceinline__ unsigned short f2bf(float f){
  uint x; __builtin_memcpy(&x, &f, 4);
  x += 0x7fffu + ((x >> 16) & 1u);           // RNE
  return (unsigned short)(x >> 16);
}
__device__ __forceinline__ uint bfpack(float a, float b){
  return (uint)f2bf(a) | ((uint)f2bf(b) << 16);
}

// async 16B global->LDS (m97-verified width). lds base must be wave-uniform;
// HW deposits lane L at base + L*16.
__device__ __forceinline__ void ld16(void* lds, const void* g){
  __builtin_amdgcn_global_load_lds((const AS1 uint*)g, (AS3 uint*)lds, 16, 0, 0);
}

// ---------------- CSR build ----------------
__global__ void k_zero(int* __restrict__ p, int n){
  int i = blockIdx.x * 256 + threadIdx.x;
  if(i < n) p[i] = 0;
}

__global__ void k_hist(const int* __restrict__ rows, int* __restrict__ deg){
  int i = blockIdx.x * 256 + threadIdx.x;           // [0, S*E)
  int s = i >> 16;                                  // E = 65536
  int r = rows[i];
  atomicAdd(&deg[s * Nv + r], 1);
}

__global__ void k_scan(const int* __restrict__ deg, int* __restrict__ rowptr, int* __restrict__ cursor){
  __shared__ int part[256];
  __shared__ int sbase[256];
  int t = threadIdx.x;
  for(int s = 0; s < Sv; s++){
    int loc[16]; int sum = 0;
    #pragma unroll
    for(int i = 0; i < 16; i++){ loc[i] = deg[s * Nv + t * 16 + i]; sum += loc[i]; }
    part[t] = sum;
    __syncthreads();
    if(t == 0){ int run = 0; for(int i = 0; i < 256; i++){ int v = part[i]; sbase[i] = run; run += v; } }
    __syncthreads();
    int run = sbase[t];
    #pragma unroll
    for(int i = 0; i < 16; i++){
      int idx = t * 16 + i;
      rowptr[s * (Nv + 1) + idx] = run;
      cursor[s * Nv + idx] = run;
      run += loc[i];
    }
    if(t == 255) rowptr[s * (Nv + 1) + Nv] = run;
    __syncthreads();
  }
}

// pack (col:u16 low, bf16(val):u16 high) -> 4 B/edge
__global__ void k_scatter(const int* __restrict__ rows, const int* __restrict__ cols,
                          const float* __restrict__ vals, int* __restrict__ cursor,
                          uint* __restrict__ pk){
  int i = blockIdx.x * 256 + threadIdx.x;           // [0, S*E)
  int s = i >> 16;
  int r = rows[i];
  int p = atomicAdd(&cursor[s * Nv + r], 1);
  pk[(s << 16) + p] = (uint)cols[i] | ((uint)f2bf(vals[i]) << 16);
}

// ---------------- build X0: bf16 [b][n][f] + fp8 copy ----------------
__global__ void k_buildx0(const float* __restrict__ inp, const float* __restrict__ st,
                          uint* __restrict__ X0bf, uint* __restrict__ X08){
  const int t = blockIdx.x * 256 + threadIdx.x;     // [0, B*N*8)
  const int c = t & 7;                              // 16-float chunk
  const int n = (t >> 3) & (Nv - 1);
  const int b = t >> 15;
  const float* src = (c < 4) ? (inp + ((size_t)b * Nv + n) * 64 + c * 16)
                             : (st  + ((size_t)b * Nv + n) * 64 + (c - 4) * 16);
  float v[16];
  #pragma unroll
  for(int q = 0; q < 4; q++){
    float4 f4 = *(const float4*)(src + q * 4);
    v[q * 4 + 0] = f4.x; v[q * 4 + 1] = f4.y; v[q * 4 + 2] = f4.z; v[q * 4 + 3] = f4.w;
  }
  const size_t base = (size_t)b * Nv + n;
  uint bfw[8];
  #pragma unroll
  for(int q = 0; q < 8; q++) bfw[q] = bfpack(v[2 * q], v[2 * q + 1]);
  *(uintx4*)(X0bf + base * 64 + c * 8)     = *(uintx4*)(bfw);
  *(uintx4*)(X0bf + base * 64 + c * 8 + 4) = *(uintx4*)(bfw + 4);
  uint f8w[4];
  #pragma unroll
  for(int q = 0; q < 4; q++){
    int w = __builtin_amdgcn_cvt_pk_fp8_f32(v[4 * q + 0], v[4 * q + 1], 0, false);
    w     = __builtin_amdgcn_cvt_pk_fp8_f32(v[4 * q + 2], v[4 * q + 3], w, true);
    f8w[q] = (uint)w;
  }
  *(uintx4*)(X08 + base * 32 + c * 4) = *(uintx4*)(f8w);
}

// ---------------- weights: Wb[m][o][f] bf16 ----------------
__global__ void k_wb(const float* __restrict__ wg, unsigned short* __restrict__ Wb){
  int t = blockIdx.x * 256 + threadIdx.x;
  if(t >= Mv * Ov * Fv) return;
  int f = t & (Fv - 1);
  int o = (t >> 7) & (Ov - 1);
  int m = t >> 14;
  Wb[t] = f2bf(wg[(f * Mv + m) * Ov + o]);
}

// ---------------- SpMM v3: fp8 gather, 8 planes/lane-group, staged edges ----------------
// wave: row r, plane-group pg (8 planes). lane: plane pg*8+(lane>>3), 16 f-elems at (lane&7)*16.
// per edge: ONE dwordx4 gather (16 fp8). 8-edge stages keep 8 gathers in flight.
__launch_bounds__(256)
__global__ void k_spmm3(const uint* __restrict__ src8,
                        uint* __restrict__ dstA, uint* __restrict__ dstB,
                        uint* __restrict__ dA8, uint* __restrict__ dB8,
                        const uint* __restrict__ xprev,
                        const int* __restrict__ rowptr, const uint* __restrict__ pk,
                        const int two_supports){
  const int lane = threadIdx.x & 63;
  const int wv   = threadIdx.x >> 6;
  int bid = blockIdx.x;
  int s = 0;
  if(two_supports){ s = bid >> 12; bid &= 4095; }
  const int pg = bid & 3;
  const int r  = (bid >> 2) * 4 + wv;
  const int p  = pg * 8 + (lane >> 3);              // plane 0..31
  const int cB = (lane & 7) * 16;                   // byte offset in 128B fp8 row
  const int* rp   = rowptr + s * (Nv + 1);
  const uint* pks = pk + (s << 16);
  const int j0 = rp[r], j1 = rp[r + 1];
  const uint* gb = src8 + (size_t)p * Nv * 32 + (cB >> 2);
  uint* dst = s ? dstB : dstA;
  uint* d8  = s ? dB8  : dA8;

  float acc[16];
  #pragma unroll
  for(int k = 0; k < 16; k++) acc[k] = 0.f;

  for(int j = j0; j < j1; j += 64){
    int rem = j1 - j; if(rem > 64) rem = 64;
    const uint e = (lane < rem) ? pks[j + lane] : 0u;   // pad: val=0, col=0
    for(int t = 0; t < rem; t += 8){
      uintx4 g[8]; float v[8];
      #pragma unroll
      for(int u = 0; u < 8; u++){
        const uint eu = __shfl(e, t + u, 64);
        v[u] = bfhi(eu);
        const uint col = eu & 0xffffu;
        g[u] = *(const uintx4*)(gb + (size_t)col * 32);
      }
      #pragma unroll
      for(int u = 0; u < 8; u++){
        #pragma unroll
        for(int d = 0; d < 4; d++){
          f32x2 lo = __builtin_amdgcn_cvt_pk_f32_fp8((int)g[u][d], false);
          f32x2 hi = __builtin_amdgcn_cvt_pk_f32_fp8((int)g[u][d], true);
          acc[d * 4 + 0] += v[u] * lo[0];
          acc[d * 4 + 1] += v[u] * lo[1];
          acc[d * 4 + 2] += v[u] * hi[0];
          acc[d * 4 + 3] += v[u] * hi[1];
        }
      }
    }
  }

  const size_t obase = (size_t)p * Nv + r;
  if(xprev){                                        // x2 = 2*A*x1 - x0
    const uint* pv = xprev + obase * 64 + (cB >> 1);
    uint pw[8];
    *(uintx4*)(pw)     = *(const uintx4*)(pv);
    *(uintx4*)(pw + 4) = *(const uintx4*)(pv + 4);
    #pragma unroll
    for(int q = 0; q < 8; q++){
      acc[2 * q + 0] = 2.f * acc[2 * q + 0] - bflo(pw[q]);
      acc[2 * q + 1] = 2.f * acc[2 * q + 1] - bfhi(pw[q]);
    }
  }
  uint bfw[8];
  #pragma unroll
  for(int q = 0; q < 8; q++) bfw[q] = bfpack(acc[2 * q], acc[2 * q + 1]);
  uint* db = dst + obase * 64 + (cB >> 1);
  __builtin_nontemporal_store(*(uintx4*)(bfw),     (uintx4*)(db));
  __builtin_nontemporal_store(*(uintx4*)(bfw + 4), (uintx4*)(db + 4));
  if(d8){
    uint f8w[4];
    #pragma unroll
    for(int q = 0; q < 4; q++){
      int w = __builtin_amdgcn_cvt_pk_fp8_f32(acc[4 * q + 0], acc[4 * q + 1], 0, false);
      w     = __builtin_amdgcn_cvt_pk_fp8_f32(acc[4 * q + 2], acc[4 * q + 3], w, true);
      f8w[q] = (uint)w;
    }
    __builtin_nontemporal_store(*(uintx4*)(f8w), (uintx4*)(d8 + obase * 32 + (cB >> 2)));
  }
}

// ---------------- GEMM with async global->LDS staging ----------------
__launch_bounds__(256)
__global__ void k_gemm(const unsigned short* __restrict__ X0,
                       const unsigned short* __restrict__ X1a,
                       const unsigned short* __restrict__ X2a,
                       const unsigned short* __restrict__ X1b,
                       const unsigned short* __restrict__ X2b,
                       const unsigned short* __restrict__ Wb,
                       const float* __restrict__ bias,
                       float* __restrict__ out){
  __shared__ unsigned short Asm[128 * 32];
  __shared__ unsigned short Bsm[128 * 32];
  const unsigned short* Am[5] = {X0, X1a, X2a, X1b, X2b};
  const int tid  = threadIdx.x;
  const int lane = tid & 63, wv = tid >> 6;
  const int wm = wv >> 1, wn = wv & 1;
  const int lrow = lane & 15, quad = lane >> 4;
  const size_t r0 = (size_t)blockIdx.x * 128;

  floatx4 acc[4][4] = {};

  #pragma unroll
  for(int m = 0; m < 5; m++){
    const unsigned short* Ab = Am[m] + r0 * Fv;
    const unsigned short* Bb = Wb + m * (Ov * Fv);
    #pragma unroll
    for(int kk = 0; kk < Fv; kk += 32){
      __syncthreads();
      #pragma unroll
      for(int p = 0; p < 2; p++){
        const int base_idx = p * 256 + wv * 64;     // wave-uniform
        const int my_idx = base_idx + lane;
        const int row = my_idx >> 2, seg = my_idx & 3;
        ld16(&Asm[base_idx * 8], Ab + (size_t)row * Fv + kk + seg * 8);
        ld16(&Bsm[base_idx * 8], Bb + row * Fv + kk + seg * 8);
      }
      __syncthreads();
      short8 af[4], bfr[4];
      #pragma unroll
      for(int t = 0; t < 4; t++){
        af[t]  = *(const short8*)(&Asm[(wm * 64 + t * 16 + lrow) * 32 + quad * 8]);
        bfr[t] = *(const short8*)(&Bsm[(wn * 64 + t * 16 + lrow) * 32 + quad * 8]);
      }
      #pragma unroll
      for(int ti = 0; ti < 4; ti++)
        #pragma unroll
        for(int tj = 0; tj < 4; tj++)
          acc[ti][tj] = __builtin_amdgcn_mfma_f32_16x16x32_bf16(af[ti], bfr[tj], acc[ti][tj], 0, 0, 0);
    }
  }

  #pragma unroll
  for(int ti = 0; ti < 4; ti++){
    #pragma unroll
    for(int tj = 0; tj < 4; tj++){
      const int col = wn * 64 + tj * 16 + lrow;
      const float bv = bias[col];
      const size_t rbase = r0 + wm * 64 + ti * 16 + quad * 4;
      #pragma unroll
      for(int t = 0; t < 4; t++){
        out[(rbase + t) * Ov + col] = acc[ti][tj][t] + bv;
      }
    }
  }
}

extern "C" void kernel_launch(void* const* d_in, const int* in_sizes, int n_in,
                              void* d_out, int out_size, void* d_ws, size_t ws_size,
                              hipStream_t stream) {
  (void)in_sizes; (void)n_in; (void)out_size; (void)ws_size;
  const float* inp  = (const float*)d_in[0];
  const float* st   = (const float*)d_in[1];
  const int*   rows = (const int*)d_in[2];
  const int*   cols = (const int*)d_in[3];
  const float* vals = (const float*)d_in[4];
  const float* wght = (const float*)d_in[5];
  const float* bias = (const float*)d_in[6];
  float* out = (float*)d_out;

  char* w = (char*)d_ws;
  const size_t SZX  = (size_t)Bv * Nv * Fv * 2;     // 32 MiB bf16 matrix
  const size_t SZX8 = (size_t)Bv * Nv * Fv;         // 16 MiB fp8 matrix
  unsigned short* X0  = (unsigned short*)(w);
  unsigned short* X1a = (unsigned short*)(w + SZX);
  unsigned short* X2a = (unsigned short*)(w + 2 * SZX);
  unsigned short* X1b = (unsigned short*)(w + 3 * SZX);
  unsigned short* X2b = (unsigned short*)(w + 4 * SZX);
  uint* X08  = (uint*)(w + 5 * SZX);
  uint* X1a8 = (uint*)(w + 5 * SZX + SZX8);
  uint* X1b8 = (uint*)(w + 5 * SZX + 2 * SZX8);
  unsigned short* Wb = (unsigned short*)(w + 5 * SZX + 3 * SZX8);
  char* p2 = w + 5 * SZX + 3 * SZX8 + 262144;
  int* deg    = (int*)p2;
  int* cursor = deg + Sv * Nv;
  int* rowptr = cursor + Sv * Nv;
  uint* pk    = (uint*)(rowptr + Sv * (Nv + 1) + 62);
  // ws use: 160 MiB bf16 + 48 MiB fp8 + ~2 MiB misc ~= 210 MiB

  k_zero<<<(Sv * Nv + 255) / 256, 256, 0, stream>>>(deg, Sv * Nv);
  k_hist<<<Sv * Ev / 256, 256, 0, stream>>>(rows, deg);
  k_scan<<<1, 256, 0, stream>>>(deg, rowptr, cursor);
  k_scatter<<<Sv * Ev / 256, 256, 0, stream>>>(rows, cols, vals, cursor, pk);
  k_buildx0<<<(Bv * Nv * 8) / 256, 256, 0, stream>>>(inp, st, (uint*)X0, X08);
  k_wb<<<(Mv * Ov * Fv + 255) / 256, 256, 0, stream>>>(wght, Wb);

  // step 1: x1 = A_s x0, both supports in one launch (same fp8 src slice per XCD)
  k_spmm3<<<8192, 256, 0, stream>>>(X08, (uint*)X1a, (uint*)X1b, X1a8, X1b8,
                                    (const uint*)nullptr, rowptr, pk, 1);
  // step 2: x2 = 2 A_s x1 - x0
  k_spmm3<<<4096, 256, 0, stream>>>(X1a8, (uint*)X2a, (uint*)X2a, nullptr, nullptr,
                                    (const uint*)X0, rowptr, pk, 0);
  k_spmm3<<<4096, 256, 0, stream>>>(X1b8, (uint*)X2b, (uint*)X2b, nullptr, nullptr,
                                    (const uint*)X0, rowptr + (Nv + 1), pk + Ev, 0);

  k_gemm<<<(Bv * Nv) / 128, 256, 0, stream>>>(X0, X1a, X2a, X1b, X2b, Wb, bias, out);
}